// Round 5
// baseline (251.314 us; speedup 1.0000x reference)
//
#include <hip/hip_runtime.h>
#include <hip/hip_bf16.h>

#define TB 2048
#define NH 16
#define HD 64
#define NE 1024
#define NB 4
#define BHD (NB * NH)      // 64 batch*heads
#define MTOK (NB * TB)     // 8192

typedef __attribute__((ext_vector_type(8))) short short8;
typedef __attribute__((ext_vector_type(4))) float f32x4;
typedef __attribute__((ext_vector_type(16))) float f32x16;
typedef __attribute__((ext_vector_type(4))) unsigned int u32x4;

static __device__ __forceinline__ unsigned short f2bf(float f) {
  __hip_bfloat16 h = __float2bfloat16(f);
  return __builtin_bit_cast(unsigned short, h);
}

#define GLDS(g, l)                                                              \
  __builtin_amdgcn_global_load_lds((const __attribute__((address_space(1))) void*)(g), \
                                   (__attribute__((address_space(3))) void*)(l), 16, 0, 0)

// ---------------- f32 -> bf16 convert (vectorized) ----------------
__global__ __launch_bounds__(256) void cvt_kernel(const float* __restrict__ in,
                                                  unsigned short* __restrict__ out,
                                                  int n4) {
  int i = blockIdx.x * blockDim.x + threadIdx.x;
  if (i >= n4) return;
  float4 v = reinterpret_cast<const float4*>(in)[i];
  ushort4 o;
  o.x = f2bf(v.x); o.y = f2bf(v.y); o.z = f2bf(v.z); o.w = f2bf(v.w);
  reinterpret_cast<ushort4*>(out)[i] = o;
}

// ---------------- RoPE cos/sin table: tab[t*32+j] = (cos, sin)(t * 10000^(-j/32)) ----------------
__global__ __launch_bounds__(256) void rope_tab_kernel(float2* __restrict__ tab) {
  int i = blockIdx.x * 256 + threadIdx.x;  // 0..65535
  int t = i >> 5, j = i & 31;
  float ang = (float)t * __builtin_exp2f(-(float)j * 0.41524101186092029f);
  float sv, cv;
  sincosf(ang, &sv, &cv);
  tab[i] = make_float2(cv, sv);
}

// ---------------- GEMM C = A * B^T (A:[M][K] bf16, B:[N][K] bf16) ----------------
template <int EPI>  // 0: plain f32 C store; 1: QKV epilogue (RoPE + scatter)
__global__ __launch_bounds__(256) void gemm_bt(
    const unsigned short* __restrict__ Am, const unsigned short* __restrict__ Bm,
    float* __restrict__ Cout, unsigned short* __restrict__ Qo,
    unsigned short* __restrict__ Ko, unsigned short* __restrict__ Vt,
    const float2* __restrict__ Tab, int Mdim, int Ndim, int Kdim) {
  __shared__ unsigned short As[128 * 64];
  __shared__ unsigned short Bs[128 * 64];

  const int tid = threadIdx.x;
  const int lane = tid & 63;
  const int w = tid >> 6;
  const int wr = w >> 1;
  const int wc = w & 1;

  // XCD-aware bijective swizzle (grid counts are multiples of 8)
  const int nwg = gridDim.x * gridDim.y;
  int bid = blockIdx.y * gridDim.x + blockIdx.x;
  const int cpx = nwg >> 3;
  bid = (bid & 7) * cpx + (bid >> 3);
  const int m0 = (bid / gridDim.x) * 128;
  const int n0 = (bid % gridDim.x) * 128;

  const int col16 = lane & 15;
  const int seg = lane >> 4;

  f32x4 acc[4][4];
#pragma unroll
  for (int i = 0; i < 4; ++i)
#pragma unroll
    for (int j = 0; j < 4; ++j) acc[i][j] = f32x4{0.f, 0.f, 0.f, 0.f};

  const int lrow = lane >> 3;            // row within 8-row chunk
  const int jg = (lane & 7) ^ lrow;      // pre-swizzled 16B-chunk col in global

  for (int kt = 0; kt < Kdim; kt += 64) {
#pragma unroll
    for (int i = 0; i < 4; ++i) {
      const int q = w * 4 + i;           // 1KB chunk id (0..15)
      const int row = q * 8 + lrow;      // tile row 0..127  (row&7 == lrow)
      GLDS(Am + (size_t)(m0 + row) * Kdim + kt + jg * 8, As + q * 512);
      GLDS(Bm + (size_t)(n0 + row) * Kdim + kt + jg * 8, Bs + q * 512);
    }
    __syncthreads();
#pragma unroll
    for (int kk = 0; kk < 2; ++kk) {
      short8 af[4], bfr[4];
#pragma unroll
      for (int mi = 0; mi < 4; ++mi) {
        const int row = wr * 64 + mi * 16 + col16;
        const int ch = (kk * 4 + seg) ^ (row & 7);
        af[mi] = *reinterpret_cast<const short8*>(
            reinterpret_cast<const char*>(As) + row * 128 + ch * 16);
      }
#pragma unroll
      for (int ni = 0; ni < 4; ++ni) {
        const int row = wc * 64 + ni * 16 + col16;
        const int ch = (kk * 4 + seg) ^ (row & 7);
        bfr[ni] = *reinterpret_cast<const short8*>(
            reinterpret_cast<const char*>(Bs) + row * 128 + ch * 16);
      }
#pragma unroll
      for (int mi = 0; mi < 4; ++mi)
#pragma unroll
        for (int ni = 0; ni < 4; ++ni)
          acc[mi][ni] = __builtin_amdgcn_mfma_f32_16x16x32_bf16(af[mi], bfr[ni],
                                                                acc[mi][ni], 0, 0, 0);
    }
    __syncthreads();
  }

  if (EPI == 0) {
#pragma unroll
    for (int mi = 0; mi < 4; ++mi)
#pragma unroll
      for (int ni = 0; ni < 4; ++ni) {
        const int gn = n0 + wc * 64 + ni * 16 + col16;
#pragma unroll
        for (int r = 0; r < 4; ++r) {
          const int gm = m0 + wr * 64 + mi * 16 + seg * 4 + r;
          Cout[(size_t)gm * Ndim + gn] = acc[mi][ni][r];
        }
      }
  } else {
    // qkv: n in [0,1024)=Q, [1024,2048)=K, [2048,3072)=V. 128|1024 so sec uniform.
    const int sec = n0 >> 10;
    const int cbase = (n0 & 1023) + wc * 64;  // multiple of 64
    const int h = cbase >> 6;
#pragma unroll
    for (int mi = 0; mi < 4; ++mi)
#pragma unroll
      for (int ni = 0; ni < 4; ++ni) {
        const int d = ni * 16 + col16;  // 0..63 head dim
        if (sec == 2) {
          // V: store transposed [BH][D][T]; 4 consecutive t per lane -> 8B store
          const int gm0 = m0 + wr * 64 + mi * 16 + seg * 4;
          const int b = gm0 >> 11;
          const int t0 = gm0 & 2047;
          ushort4 pv;
          pv.x = f2bf(acc[mi][ni][0]);
          pv.y = f2bf(acc[mi][ni][1]);
          pv.z = f2bf(acc[mi][ni][2]);
          pv.w = f2bf(acc[mi][ni][3]);
          *reinterpret_cast<ushort4*>(
              Vt + ((size_t)((b * NH + h) * HD + d)) * TB + t0) = pv;
        } else {
          // RoPE via precomputed table: angle a_d = t * 10000^(-(d%32)/32)
          const float sgn = (d & 1) ? 1.f : -1.f;
          const int j = d & 31;
#pragma unroll
          for (int r = 0; r < 4; ++r) {
            const int gm = m0 + wr * 64 + mi * 16 + seg * 4 + r;
            const int b = gm >> 11;
            const int t = gm & 2047;
            const float v = acc[mi][ni][r];
            const float p = __shfl_xor(v, 1);  // pair partner (adjacent col)
            const float2 csv = Tab[t * 32 + j];
            float rot = v * csv.x + sgn * p * csv.y;
            // fold 1/sqrt(D) AND log2(e) into Q so attn softmax can use exp2
            if (sec == 0) rot *= 0.18033688011112042f;  // 0.125 * log2(e)
            unsigned short* dst = (sec == 0) ? Qo : Ko;
            dst[((size_t)(b * NH + h) * TB + t) * HD + d] = f2bf(rot);
          }
        }
      }
  }
}

// ---------------- causal flash attention v3: swapped 32x32, reg-pipelined ----------------
// One wave per 32-q tile. Block mixes long+short tiles: waves 0,1 -> qt=p,
// waves 2,3 -> qt=63-p (uniform block work, no tail). Per iter (64 kv):
// QK^T uses preloaded K frags; V frags issued before softmax (latency cover);
// next-iter K frags issued right after QK^T. Softmax in-register with
// defer-max (skip rescale when max didn't grow by >8 in exp2 domain).
__global__ __launch_bounds__(256) void attn_kernel(
    const unsigned short* __restrict__ Q, const unsigned short* __restrict__ K,
    const unsigned short* __restrict__ Vt, unsigned short* __restrict__ Ao) {
  const int tid = threadIdx.x;
  const int lane = tid & 63;
  const int w = tid >> 6;
  const int b = blockIdx.x;
  const int p = b >> 5;                  // qt-pair 0..31
  const int c = b & 31;                  // bh-pair 0..31
  const int bh = (c << 1) | (w & 1);
  const int qt = (w & 2) ? (63 - p) : p;
  const int q0 = qt << 5;
  const int l31 = lane & 31;
  const int hi = lane >> 5;
  const int qm = l31 - 4 * hi;          // diag mask: kill reg r if rowbase(r) > qm

  const unsigned short* Qp = Q + (size_t)bh * TB * HD + (size_t)(q0 + l31) * HD + hi * 8;
  const unsigned short* Kc = K + (size_t)bh * TB * HD + (size_t)l31 * HD + hi * 8;
  const unsigned short* Vc = Vt + (size_t)bh * HD * TB + (size_t)l31 * TB + hi * 8;

  short8 qf[4];
#pragma unroll
  for (int s = 0; s < 4; ++s)
    qf[s] = *reinterpret_cast<const short8*>(Qp + s * 16);

  f32x16 o0, o1;
#pragma unroll
  for (int r = 0; r < 16; ++r) { o0[r] = 0.f; o1[r] = 0.f; }
  float mrow = -1e30f, lsum = 0.f;

  // preload K fragments for iter 0
  short8 kf0[4], kf1[4];
#pragma unroll
  for (int s = 0; s < 4; ++s)
    kf0[s] = *reinterpret_cast<const short8*>(Kc + s * 16);
  if (q0 >= 32)
#pragma unroll
    for (int s = 0; s < 4; ++s)
      kf1[s] = *reinterpret_cast<const short8*>(Kc + 32 * HD + s * 16);

#define MASKDIAG(st)                                                            \
  { _Pragma("unroll") for (int r = 0; r < 16; ++r) {                            \
      const int rowb = (r & 3) + 8 * (r >> 2);                                  \
      if (rowb > qm) st[r] = -1e30f; } }

  // PV for one 32-kv S-tile: pack P to bf16, lane^32 word exchange builds the
  // P^T B-frags, O^T += V^T * P^T.
#define PVTILE(st, V0, V1, V2, V3)                                              \
  {                                                                             \
    unsigned int wd[8];                                                         \
    _Pragma("unroll") for (int i = 0; i < 8; ++i)                               \
      wd[i] = (unsigned int)f2bf(st[2 * i]) |                                   \
              ((unsigned int)f2bf(st[2 * i + 1]) << 16);                        \
    unsigned int ex0 = __shfl_xor(hi ? wd[0] : wd[2], 32);                      \
    unsigned int ex1 = __shfl_xor(hi ? wd[1] : wd[3], 32);                      \
    unsigned int ex2 = __shfl_xor(hi ? wd[4] : wd[6], 32);                      \
    unsigned int ex3 = __shfl_xor(hi ? wd[5] : wd[7], 32);                      \
    u32x4 f0, f1;                                                               \
    f0[0] = hi ? ex0 : wd[0]; f0[1] = hi ? ex1 : wd[1];                         \
    f0[2] = hi ? wd[2] : ex0; f0[3] = hi ? wd[3] : ex1;                         \
    f1[0] = hi ? ex2 : wd[4]; f1[1] = hi ? ex3 : wd[5];                         \
    f1[2] = hi ? wd[6] : ex2; f1[3] = hi ? wd[7] : ex3;                         \
    short8 p0 = __builtin_bit_cast(short8, f0);                                 \
    short8 p1 = __builtin_bit_cast(short8, f1);                                 \
    __builtin_amdgcn_s_setprio(1);                                              \
    o0 = __builtin_amdgcn_mfma_f32_32x32x16_bf16(V0, p0, o0, 0, 0, 0);          \
    o1 = __builtin_amdgcn_mfma_f32_32x32x16_bf16(V1, p0, o1, 0, 0, 0);          \
    o0 = __builtin_amdgcn_mfma_f32_32x32x16_bf16(V2, p1, o0, 0, 0, 0);          \
    o1 = __builtin_amdgcn_mfma_f32_32x32x16_bf16(V3, p1, o1, 0, 0, 0);          \
    __builtin_amdgcn_s_setprio(0);                                              \
  }

  const int L = qt >> 1;
  for (int kt = 0; kt <= L; ++kt) {
    const int kv0 = kt << 6;
    const bool two = (kv0 + 32 <= q0);

    // QK^T (S^T accumulate) with preloaded K frags
    f32x16 s0, s1;
#pragma unroll
    for (int r = 0; r < 16; ++r) { s0[r] = 0.f; s1[r] = 0.f; }
    __builtin_amdgcn_s_setprio(1);
#pragma unroll
    for (int s = 0; s < 4; ++s)
      s0 = __builtin_amdgcn_mfma_f32_32x32x16_bf16(kf0[s], qf[s], s0, 0, 0, 0);
    if (two)
#pragma unroll
      for (int s = 0; s < 4; ++s)
        s1 = __builtin_amdgcn_mfma_f32_32x32x16_bf16(kf1[s], qf[s], s1, 0, 0, 0);
    __builtin_amdgcn_s_setprio(0);

    // V fragments for THIS iter: issued now, consumed after softmax (~400cy cover)
    short8 va0 = *reinterpret_cast<const short8*>(Vc);
    short8 va1 = *reinterpret_cast<const short8*>(Vc + 32 * TB);
    short8 va2 = *reinterpret_cast<const short8*>(Vc + 16);
    short8 va3 = *reinterpret_cast<const short8*>(Vc + 32 * TB + 16);
    short8 vb0, vb1, vb2, vb3;
    if (two) {
      vb0 = *reinterpret_cast<const short8*>(Vc + 32);
      vb1 = *reinterpret_cast<const short8*>(Vc + 32 * TB + 32);
      vb2 = *reinterpret_cast<const short8*>(Vc + 48);
      vb3 = *reinterpret_cast<const short8*>(Vc + 32 * TB + 48);
    }

    // K fragments for NEXT iter: issued now, consumed next QK^T (~600cy cover)
    if (kt < L) {
      const unsigned short* Kn = Kc + 64 * HD;
#pragma unroll
      for (int s = 0; s < 4; ++s)
        kf0[s] = *reinterpret_cast<const short8*>(Kn + s * 16);
      if (kv0 + 96 <= q0)
#pragma unroll
        for (int s = 0; s < 4; ++s)
          kf1[s] = *reinterpret_cast<const short8*>(Kn + 32 * HD + s * 16);
    }

    // causal mask on the diagonal 32x32 tile
    if (kv0 == q0) MASKDIAG(s0);
    if (two && (kv0 + 32 == q0)) MASKDIAG(s1);

    // online softmax in exp2 domain (Q pre-scaled by 0.125*log2e), defer-max
    float pm = s0[0];
#pragma unroll
    for (int r = 1; r < 16; ++r) pm = fmaxf(pm, s0[r]);
    if (two)
#pragma unroll
      for (int r = 0; r < 16; ++r) pm = fmaxf(pm, s1[r]);
    pm = fmaxf(pm, __shfl_xor(pm, 32));
    if (!__all(pm - mrow <= 8.f)) {
      const float mn = fmaxf(mrow, pm);
      const float fs = __builtin_exp2f(mrow - mn);
      mrow = mn;
      lsum *= fs;
#pragma unroll
      for (int r = 0; r < 16; ++r) { o0[r] *= fs; o1[r] *= fs; }
    }
    float rs = 0.f;
#pragma unroll
    for (int r = 0; r < 16; ++r) { s0[r] = __builtin_exp2f(s0[r] - mrow); rs += s0[r]; }
    if (two)
#pragma unroll
      for (int r = 0; r < 16; ++r) { s1[r] = __builtin_exp2f(s1[r] - mrow); rs += s1[r]; }
    rs += __shfl_xor(rs, 32);
    lsum += rs;

    PVTILE(s0, va0, va1, va2, va3);
    if (two) PVTILE(s1, vb0, vb1, vb2, vb3);

    Vc += 64;
    Kc += 64 * HD;
  }

  // epilogue: normalize (lsum lane-uniform per q) and store bf16 to Ao[B][T][E]
  const float inv = 1.f / lsum;
  const int batch = bh >> 4;
  const int h = bh & 15;
  unsigned short* Aor = Ao + ((size_t)(batch * TB + q0 + l31)) * NE + (h << 6);
#pragma unroll
  for (int dt = 0; dt < 2; ++dt) {
#pragma unroll
    for (int qd = 0; qd < 4; ++qd) {
      ushort4 pk;
      pk.x = f2bf((dt ? o1[4 * qd + 0] : o0[4 * qd + 0]) * inv);
      pk.y = f2bf((dt ? o1[4 * qd + 1] : o0[4 * qd + 1]) * inv);
      pk.z = f2bf((dt ? o1[4 * qd + 2] : o0[4 * qd + 2]) * inv);
      pk.w = f2bf((dt ? o1[4 * qd + 3] : o0[4 * qd + 3]) * inv);
      *reinterpret_cast<ushort4*>(Aor + dt * 32 + 8 * qd + 4 * hi) = pk;
    }
  }
#undef MASKDIAG
#undef PVTILE
}

// ---------------- launch ----------------
extern "C" void kernel_launch(void* const* d_in, const int* in_sizes, int n_in,
                              void* d_out, int out_size, void* d_ws, size_t ws_size,
                              hipStream_t stream) {
  const float* x = (const float*)d_in[0];
  const float* w_attn = (const float*)d_in[1];
  const float* w_proj = (const float*)d_in[2];
  float* out = (float*)d_out;
  char* ws = (char*)d_ws;

  const size_t SZ_XB = (size_t)MTOK * NE * 2;        // 16 MiB
  const size_t SZ_WA = (size_t)3 * NE * NE * 2;      // 6 MiB
  const size_t SZ_WP = (size_t)NE * NE * 2;          // 2 MiB
  const size_t SZ_T = (size_t)BHD * TB * HD * 2;     // 16 MiB

  unsigned short* xb = (unsigned short*)(ws);
  unsigned short* wab = (unsigned short*)(ws + SZ_XB);
  unsigned short* wpb = (unsigned short*)(ws + SZ_XB + SZ_WA);
  unsigned short* Qs = (unsigned short*)(ws + SZ_XB + SZ_WA + SZ_WP);
  unsigned short* Ks = (unsigned short*)(ws + SZ_XB + SZ_WA + SZ_WP + SZ_T);
  unsigned short* Vt = (unsigned short*)(ws + SZ_XB + SZ_WA + SZ_WP + 2 * SZ_T);
  unsigned short* Ao = (unsigned short*)(ws + SZ_XB + SZ_WA + SZ_WP + 3 * SZ_T);
  // RoPE table lives in Ao's space: needed only by gemm<1>, dead before attn writes Ao
  float2* tab = (float2*)Ao;

  hipLaunchKernelGGL(cvt_kernel, dim3(MTOK * NE / 4 / 256), dim3(256), 0, stream,
                     x, xb, MTOK * NE / 4);
  hipLaunchKernelGGL(cvt_kernel, dim3(3 * NE * NE / 4 / 256), dim3(256), 0, stream,
                     w_attn, wab, 3 * NE * NE / 4);
  hipLaunchKernelGGL(cvt_kernel, dim3(NE * NE / 4 / 256), dim3(256), 0, stream,
                     w_proj, wpb, NE * NE / 4);
  hipLaunchKernelGGL(rope_tab_kernel, dim3(TB * 32 / 256), dim3(256), 0, stream, tab);

  hipLaunchKernelGGL((gemm_bt<1>), dim3(3 * NE / 128, MTOK / 128), dim3(256), 0,
                     stream, xb, wab, nullptr, Qs, Ks, Vt, tab, MTOK, 3 * NE, NE);

  // 32 qt-pairs * 32 bh-pairs = 1024 blocks; each block: waves 0,1 -> qt=p, 2,3 -> 63-p
  hipLaunchKernelGGL(attn_kernel, dim3(1024), dim3(256), 0, stream,
                     Qs, Ks, Vt, Ao);

  hipLaunchKernelGGL((gemm_bt<0>), dim3(NE / 128, MTOK / 128), dim3(256), 0,
                     stream, Ao, wpb, out, nullptr, nullptr, nullptr,
                     (const float2*)nullptr, MTOK, NE, NE);
}

// Round 6
// 241.963 us; speedup vs baseline: 1.0386x; 1.0386x over previous
//
#include <hip/hip_runtime.h>
#include <hip/hip_bf16.h>

#define TB 2048
#define NH 16
#define HD 64
#define NE 1024
#define NB 4
#define BHD (NB * NH)      // 64 batch*heads
#define MTOK (NB * TB)     // 8192

typedef __attribute__((ext_vector_type(8))) short short8;
typedef __attribute__((ext_vector_type(4))) float f32x4;
typedef __attribute__((ext_vector_type(16))) float f32x16;
typedef __attribute__((ext_vector_type(4))) unsigned int u32x4;

static __device__ __forceinline__ unsigned short f2bf(float f) {
  __hip_bfloat16 h = __float2bfloat16(f);
  return __builtin_bit_cast(unsigned short, h);
}

#define GLDS(g, l)                                                              \
  __builtin_amdgcn_global_load_lds((const __attribute__((address_space(1))) void*)(g), \
                                   (__attribute__((address_space(3))) void*)(l), 16, 0, 0)

// ---------------- f32 -> bf16 convert (vectorized) ----------------
__global__ __launch_bounds__(256) void cvt_kernel(const float* __restrict__ in,
                                                  unsigned short* __restrict__ out,
                                                  int n4) {
  int i = blockIdx.x * blockDim.x + threadIdx.x;
  if (i >= n4) return;
  float4 v = reinterpret_cast<const float4*>(in)[i];
  ushort4 o;
  o.x = f2bf(v.x); o.y = f2bf(v.y); o.z = f2bf(v.z); o.w = f2bf(v.w);
  reinterpret_cast<ushort4*>(out)[i] = o;
}

// ---------------- RoPE cos/sin table: tab[t*32+j] = (cos, sin)(t * 10000^(-j/32)) ----------------
__global__ __launch_bounds__(256) void rope_tab_kernel(float2* __restrict__ tab) {
  int i = blockIdx.x * 256 + threadIdx.x;  // 0..65535
  int t = i >> 5, j = i & 31;
  float ang = (float)t * __builtin_exp2f(-(float)j * 0.41524101186092029f);
  float sv, cv;
  sincosf(ang, &sv, &cv);
  tab[i] = make_float2(cv, sv);
}

// ---------------- GEMM C = A * B^T (A:[M][K] bf16, B:[N][K] bf16) ----------------
template <int EPI>  // 0: plain f32 C store; 1: QKV epilogue (RoPE + scatter)
__global__ __launch_bounds__(256) void gemm_bt(
    const unsigned short* __restrict__ Am, const unsigned short* __restrict__ Bm,
    float* __restrict__ Cout, unsigned short* __restrict__ Qo,
    unsigned short* __restrict__ Ko, unsigned short* __restrict__ Vt,
    const float2* __restrict__ Tab, int Mdim, int Ndim, int Kdim) {
  __shared__ unsigned short As[128 * 64];
  __shared__ unsigned short Bs[128 * 64];

  const int tid = threadIdx.x;
  const int lane = tid & 63;
  const int w = tid >> 6;
  const int wr = w >> 1;
  const int wc = w & 1;

  // XCD-aware bijective swizzle (grid counts are multiples of 8)
  const int nwg = gridDim.x * gridDim.y;
  int bid = blockIdx.y * gridDim.x + blockIdx.x;
  const int cpx = nwg >> 3;
  bid = (bid & 7) * cpx + (bid >> 3);
  const int m0 = (bid / gridDim.x) * 128;
  const int n0 = (bid % gridDim.x) * 128;

  const int col16 = lane & 15;
  const int seg = lane >> 4;

  f32x4 acc[4][4];
#pragma unroll
  for (int i = 0; i < 4; ++i)
#pragma unroll
    for (int j = 0; j < 4; ++j) acc[i][j] = f32x4{0.f, 0.f, 0.f, 0.f};

  const int lrow = lane >> 3;            // row within 8-row chunk
  const int jg = (lane & 7) ^ lrow;      // pre-swizzled 16B-chunk col in global

  for (int kt = 0; kt < Kdim; kt += 64) {
#pragma unroll
    for (int i = 0; i < 4; ++i) {
      const int q = w * 4 + i;           // 1KB chunk id (0..15)
      const int row = q * 8 + lrow;      // tile row 0..127  (row&7 == lrow)
      GLDS(Am + (size_t)(m0 + row) * Kdim + kt + jg * 8, As + q * 512);
      GLDS(Bm + (size_t)(n0 + row) * Kdim + kt + jg * 8, Bs + q * 512);
    }
    __syncthreads();
#pragma unroll
    for (int kk = 0; kk < 2; ++kk) {
      short8 af[4], bfr[4];
#pragma unroll
      for (int mi = 0; mi < 4; ++mi) {
        const int row = wr * 64 + mi * 16 + col16;
        const int ch = (kk * 4 + seg) ^ (row & 7);
        af[mi] = *reinterpret_cast<const short8*>(
            reinterpret_cast<const char*>(As) + row * 128 + ch * 16);
      }
#pragma unroll
      for (int ni = 0; ni < 4; ++ni) {
        const int row = wc * 64 + ni * 16 + col16;
        const int ch = (kk * 4 + seg) ^ (row & 7);
        bfr[ni] = *reinterpret_cast<const short8*>(
            reinterpret_cast<const char*>(Bs) + row * 128 + ch * 16);
      }
#pragma unroll
      for (int mi = 0; mi < 4; ++mi)
#pragma unroll
        for (int ni = 0; ni < 4; ++ni)
          acc[mi][ni] = __builtin_amdgcn_mfma_f32_16x16x32_bf16(af[mi], bfr[ni],
                                                                acc[mi][ni], 0, 0, 0);
    }
    __syncthreads();
  }

  if (EPI == 0) {
#pragma unroll
    for (int mi = 0; mi < 4; ++mi)
#pragma unroll
      for (int ni = 0; ni < 4; ++ni) {
        const int gn = n0 + wc * 64 + ni * 16 + col16;
#pragma unroll
        for (int r = 0; r < 4; ++r) {
          const int gm = m0 + wr * 64 + mi * 16 + seg * 4 + r;
          Cout[(size_t)gm * Ndim + gn] = acc[mi][ni][r];
        }
      }
  } else {
    // qkv: n in [0,1024)=Q, [1024,2048)=K, [2048,3072)=V. 128|1024 so sec uniform.
    const int sec = n0 >> 10;
    const int cbase = (n0 & 1023) + wc * 64;  // multiple of 64
    const int h = cbase >> 6;
#pragma unroll
    for (int mi = 0; mi < 4; ++mi)
#pragma unroll
      for (int ni = 0; ni < 4; ++ni) {
        const int d = ni * 16 + col16;  // 0..63 head dim
        if (sec == 2) {
          // V: store transposed [BH][D][T]; 4 consecutive t per lane -> 8B store
          const int gm0 = m0 + wr * 64 + mi * 16 + seg * 4;
          const int b = gm0 >> 11;
          const int t0 = gm0 & 2047;
          ushort4 pv;
          pv.x = f2bf(acc[mi][ni][0]);
          pv.y = f2bf(acc[mi][ni][1]);
          pv.z = f2bf(acc[mi][ni][2]);
          pv.w = f2bf(acc[mi][ni][3]);
          *reinterpret_cast<ushort4*>(
              Vt + ((size_t)((b * NH + h) * HD + d)) * TB + t0) = pv;
        } else {
          // RoPE via precomputed table: angle a_d = t * 10000^(-(d%32)/32)
          const float sgn = (d & 1) ? 1.f : -1.f;
          const int j = d & 31;
#pragma unroll
          for (int r = 0; r < 4; ++r) {
            const int gm = m0 + wr * 64 + mi * 16 + seg * 4 + r;
            const int b = gm >> 11;
            const int t = gm & 2047;
            const float v = acc[mi][ni][r];
            const float p = __shfl_xor(v, 1);  // pair partner (adjacent col)
            const float2 csv = Tab[t * 32 + j];
            float rot = v * csv.x + sgn * p * csv.y;
            // fold 1/sqrt(D) AND log2(e) into Q so attn softmax can use exp2
            if (sec == 0) rot *= 0.18033688011112042f;  // 0.125 * log2(e)
            unsigned short* dst = (sec == 0) ? Qo : Ko;
            dst[((size_t)(b * NH + h) * TB + t) * HD + d] = f2bf(rot);
          }
        }
      }
  }
}

// ---------------- causal flash attention v4: swapped 32x32, balanced pairs ----------------
// Each WAVE processes q-tile pair {pr, 63-pr} for one bh sequentially: exactly
// 65 S-tiles (32-kv) per wave -> perfectly uniform duration, no tail.
// 512 blocks x 4 waves = 2048 waves = steady 2 waves/SIMD.
// In-register softmax; P pack via v_cvt_pk_bf16_f32; P^T fragment exchange via
// v_permlane32_swap_b32 (replaces ds_bpermute shfl + cndmask selects).
__global__ __launch_bounds__(256) void attn_kernel(
    const unsigned short* __restrict__ Q, const unsigned short* __restrict__ K,
    const unsigned short* __restrict__ Vt, unsigned short* __restrict__ Ao) {
  const int tid = threadIdx.x;
  const int lane = tid & 63;
  const int w = tid >> 6;
  // XCD swizzle: phys block b lands on XCD (b&7); remap so each XCD serves a
  // contiguous 64-block range = 8 consecutive bh (K/V 4MB = one L2).
  const int L = ((int)blockIdx.x & 7) * 64 + ((int)blockIdx.x >> 3);
  const int wid = L * 4 + w;            // 0..2047
  const int bh = wid >> 5;              // 0..63
  const int pr = wid & 31;              // 0..31
  const int l31 = lane & 31;
  const int hi = lane >> 5;
  const int qm = l31 - 4 * hi;          // diag mask: kill reg r if rowbase(r) > qm

  const unsigned short* Qb = Q + (size_t)bh * TB * HD;
  const unsigned short* Kb = K + (size_t)bh * TB * HD + (size_t)l31 * HD + hi * 8;
  const unsigned short* Vb = Vt + (size_t)bh * HD * TB + (size_t)l31 * TB + hi * 8;

  const int batch = bh >> 4;
  const int h = bh & 15;

#define MASKDIAG(st)                                                            \
  { _Pragma("unroll") for (int r = 0; r < 16; ++r) {                            \
      const int rowb = (r & 3) + 8 * (r >> 2);                                  \
      if (rowb > qm) st[r] = -1e30f; } }

  // P pack + P^T B-frag build + PV accumulate for one 32-kv S-tile.
#define PVTILE(st, V0, V1, V2, V3)                                              \
  {                                                                             \
    unsigned int wd[8];                                                         \
    _Pragma("unroll") for (int i = 0; i < 8; ++i) {                             \
      unsigned int t_;                                                          \
      asm("v_cvt_pk_bf16_f32 %0, %1, %2"                                        \
          : "=v"(t_) : "v"(st[2 * i]), "v"(st[2 * i + 1]));                     \
      wd[i] = t_;                                                               \
    }                                                                           \
    asm("v_permlane32_swap_b32 %0, %1" : "+v"(wd[0]), "+v"(wd[2]));             \
    asm("v_permlane32_swap_b32 %0, %1" : "+v"(wd[1]), "+v"(wd[3]));             \
    asm("v_permlane32_swap_b32 %0, %1" : "+v"(wd[4]), "+v"(wd[6]));             \
    asm("v_permlane32_swap_b32 %0, %1" : "+v"(wd[5]), "+v"(wd[7]));             \
    u32x4 f0 = {wd[0], wd[1], wd[2], wd[3]};                                    \
    u32x4 f1 = {wd[4], wd[5], wd[6], wd[7]};                                    \
    short8 p0 = __builtin_bit_cast(short8, f0);                                 \
    short8 p1 = __builtin_bit_cast(short8, f1);                                 \
    __builtin_amdgcn_s_setprio(1);                                              \
    o0 = __builtin_amdgcn_mfma_f32_32x32x16_bf16(V0, p0, o0, 0, 0, 0);          \
    o1 = __builtin_amdgcn_mfma_f32_32x32x16_bf16(V1, p0, o1, 0, 0, 0);          \
    o0 = __builtin_amdgcn_mfma_f32_32x32x16_bf16(V2, p1, o0, 0, 0, 0);          \
    o1 = __builtin_amdgcn_mfma_f32_32x32x16_bf16(V3, p1, o1, 0, 0, 0);          \
    __builtin_amdgcn_s_setprio(0);                                              \
  }

#pragma unroll 1
  for (int ph = 0; ph < 2; ++ph) {
    const int qt = ph ? (63 - pr) : pr;
    const int q0 = qt << 5;
    const unsigned short* Kc = Kb;
    const unsigned short* Vc = Vb;

    short8 qf[4];
#pragma unroll
    for (int s = 0; s < 4; ++s)
      qf[s] = *reinterpret_cast<const short8*>(
          Qb + (size_t)(q0 + l31) * HD + hi * 8 + s * 16);

    f32x16 o0, o1;
#pragma unroll
    for (int r = 0; r < 16; ++r) { o0[r] = 0.f; o1[r] = 0.f; }
    float mrow = -1e30f, lsum = 0.f;

    // preload K fragments for iter 0
    short8 kf0[4], kf1[4];
#pragma unroll
    for (int s = 0; s < 4; ++s)
      kf0[s] = *reinterpret_cast<const short8*>(Kc + s * 16);
    if (q0 >= 32)
#pragma unroll
      for (int s = 0; s < 4; ++s)
        kf1[s] = *reinterpret_cast<const short8*>(Kc + 32 * HD + s * 16);

    const int LI = qt >> 1;
    for (int kt = 0; kt <= LI; ++kt) {
      const int kv0 = kt << 6;
      const bool two = (kv0 + 32 <= q0);

      // QK^T (S^T accumulate) with preloaded K frags
      f32x16 s0, s1;
#pragma unroll
      for (int r = 0; r < 16; ++r) { s0[r] = 0.f; s1[r] = 0.f; }
      __builtin_amdgcn_s_setprio(1);
#pragma unroll
      for (int s = 0; s < 4; ++s)
        s0 = __builtin_amdgcn_mfma_f32_32x32x16_bf16(kf0[s], qf[s], s0, 0, 0, 0);
      if (two)
#pragma unroll
        for (int s = 0; s < 4; ++s)
          s1 = __builtin_amdgcn_mfma_f32_32x32x16_bf16(kf1[s], qf[s], s1, 0, 0, 0);
      __builtin_amdgcn_s_setprio(0);

      // V frags for THIS iter (consumed after softmax; latency covered)
      short8 va0 = *reinterpret_cast<const short8*>(Vc);
      short8 va1 = *reinterpret_cast<const short8*>(Vc + 32 * TB);
      short8 va2 = *reinterpret_cast<const short8*>(Vc + 16);
      short8 va3 = *reinterpret_cast<const short8*>(Vc + 32 * TB + 16);
      short8 vb0, vb1, vb2, vb3;
      if (two) {
        vb0 = *reinterpret_cast<const short8*>(Vc + 32);
        vb1 = *reinterpret_cast<const short8*>(Vc + 32 * TB + 32);
        vb2 = *reinterpret_cast<const short8*>(Vc + 48);
        vb3 = *reinterpret_cast<const short8*>(Vc + 32 * TB + 48);
      }

      // K frags for NEXT iter
      if (kt < LI) {
        const unsigned short* Kn = Kc + 64 * HD;
#pragma unroll
        for (int s = 0; s < 4; ++s)
          kf0[s] = *reinterpret_cast<const short8*>(Kn + s * 16);
        if (kv0 + 96 <= q0)
#pragma unroll
          for (int s = 0; s < 4; ++s)
            kf1[s] = *reinterpret_cast<const short8*>(Kn + 32 * HD + s * 16);
      }

      // causal mask on the diagonal 32x32 tile
      if (kv0 == q0) MASKDIAG(s0);
      if (two && (kv0 + 32 == q0)) MASKDIAG(s1);

      // online softmax (exp2 domain; Q pre-scaled by 0.125*log2e), defer-max,
      // tree-shaped reductions (depth 4 instead of 15/31).
      float mx[8];
#pragma unroll
      for (int i = 0; i < 8; ++i) mx[i] = fmaxf(s0[2 * i], s0[2 * i + 1]);
      if (two)
#pragma unroll
        for (int i = 0; i < 8; ++i)
          mx[i] = fmaxf(mx[i], fmaxf(s1[2 * i], s1[2 * i + 1]));
#pragma unroll
      for (int i = 0; i < 4; ++i) mx[i] = fmaxf(mx[i], mx[i + 4]);
      float pm = fmaxf(fmaxf(mx[0], mx[1]), fmaxf(mx[2], mx[3]));
      pm = fmaxf(pm, __shfl_xor(pm, 32));
      if (!__all(pm - mrow <= 8.f)) {
        const float mn = fmaxf(mrow, pm);
        const float fs = __builtin_exp2f(mrow - mn);
        mrow = mn;
        lsum *= fs;
#pragma unroll
        for (int r = 0; r < 16; ++r) { o0[r] *= fs; o1[r] *= fs; }
      }
      float sm[8];
#pragma unroll
      for (int i = 0; i < 8; ++i) {
        s0[2 * i] = __builtin_exp2f(s0[2 * i] - mrow);
        s0[2 * i + 1] = __builtin_exp2f(s0[2 * i + 1] - mrow);
        sm[i] = s0[2 * i] + s0[2 * i + 1];
      }
      if (two)
#pragma unroll
        for (int i = 0; i < 8; ++i) {
          s1[2 * i] = __builtin_exp2f(s1[2 * i] - mrow);
          s1[2 * i + 1] = __builtin_exp2f(s1[2 * i + 1] - mrow);
          sm[i] += s1[2 * i] + s1[2 * i + 1];
        }
#pragma unroll
      for (int i = 0; i < 4; ++i) sm[i] += sm[i + 4];
      float rs = (sm[0] + sm[1]) + (sm[2] + sm[3]);
      rs += __shfl_xor(rs, 32);
      lsum += rs;

      PVTILE(s0, va0, va1, va2, va3);
      if (two) PVTILE(s1, vb0, vb1, vb2, vb3);

      Vc += 64;
      Kc += 64 * HD;
    }

    // epilogue: normalize (lsum lane-uniform per q) and store bf16 to Ao[B][T][E]
    const float inv = 1.f / lsum;
    unsigned short* Aor = Ao + ((size_t)(batch * TB + q0 + l31)) * NE + (h << 6);
#pragma unroll
    for (int dt = 0; dt < 2; ++dt) {
#pragma unroll
      for (int qd = 0; qd < 4; ++qd) {
        ushort4 pk;
        pk.x = f2bf((dt ? o1[4 * qd + 0] : o0[4 * qd + 0]) * inv);
        pk.y = f2bf((dt ? o1[4 * qd + 1] : o0[4 * qd + 1]) * inv);
        pk.z = f2bf((dt ? o1[4 * qd + 2] : o0[4 * qd + 2]) * inv);
        pk.w = f2bf((dt ? o1[4 * qd + 3] : o0[4 * qd + 3]) * inv);
        *reinterpret_cast<ushort4*>(Aor + dt * 32 + 8 * qd + 4 * hi) = pk;
      }
    }
  }
#undef MASKDIAG
#undef PVTILE
}

// ---------------- launch ----------------
extern "C" void kernel_launch(void* const* d_in, const int* in_sizes, int n_in,
                              void* d_out, int out_size, void* d_ws, size_t ws_size,
                              hipStream_t stream) {
  const float* x = (const float*)d_in[0];
  const float* w_attn = (const float*)d_in[1];
  const float* w_proj = (const float*)d_in[2];
  float* out = (float*)d_out;
  char* ws = (char*)d_ws;

  const size_t SZ_XB = (size_t)MTOK * NE * 2;        // 16 MiB
  const size_t SZ_WA = (size_t)3 * NE * NE * 2;      // 6 MiB
  const size_t SZ_WP = (size_t)NE * NE * 2;          // 2 MiB
  const size_t SZ_T = (size_t)BHD * TB * HD * 2;     // 16 MiB

  unsigned short* xb = (unsigned short*)(ws);
  unsigned short* wab = (unsigned short*)(ws + SZ_XB);
  unsigned short* wpb = (unsigned short*)(ws + SZ_XB + SZ_WA);
  unsigned short* Qs = (unsigned short*)(ws + SZ_XB + SZ_WA + SZ_WP);
  unsigned short* Ks = (unsigned short*)(ws + SZ_XB + SZ_WA + SZ_WP + SZ_T);
  unsigned short* Vt = (unsigned short*)(ws + SZ_XB + SZ_WA + SZ_WP + 2 * SZ_T);
  unsigned short* Ao = (unsigned short*)(ws + SZ_XB + SZ_WA + SZ_WP + 3 * SZ_T);
  // RoPE table lives in Ao's space: needed only by gemm<1>, dead before attn writes Ao
  float2* tab = (float2*)Ao;

  hipLaunchKernelGGL(cvt_kernel, dim3(MTOK * NE / 4 / 256), dim3(256), 0, stream,
                     x, xb, MTOK * NE / 4);
  hipLaunchKernelGGL(cvt_kernel, dim3(3 * NE * NE / 4 / 256), dim3(256), 0, stream,
                     w_attn, wab, 3 * NE * NE / 4);
  hipLaunchKernelGGL(cvt_kernel, dim3(NE * NE / 4 / 256), dim3(256), 0, stream,
                     w_proj, wpb, NE * NE / 4);
  hipLaunchKernelGGL(rope_tab_kernel, dim3(TB * 32 / 256), dim3(256), 0, stream, tab);

  hipLaunchKernelGGL((gemm_bt<1>), dim3(3 * NE / 128, MTOK / 128), dim3(256), 0,
                     stream, xb, wab, nullptr, Qs, Ks, Vt, tab, MTOK, 3 * NE, NE);

  // 512 blocks x 4 waves; each wave does q-tile pair {pr, 63-pr} for one bh
  hipLaunchKernelGGL(attn_kernel, dim3(512), dim3(256), 0, stream,
                     Qs, Ks, Vt, Ao);

  hipLaunchKernelGGL((gemm_bt<0>), dim3(NE / 128, MTOK / 128), dim3(256), 0,
                     stream, Ao, wpb, out, nullptr, nullptr, nullptr,
                     (const float2*)nullptr, MTOK, NE, NE);
}

// Round 7
// 238.997 us; speedup vs baseline: 1.0515x; 1.0124x over previous
//
#include <hip/hip_runtime.h>
#include <hip/hip_bf16.h>

#define TB 2048
#define NH 16
#define HD 64
#define NE 1024
#define NB 4
#define BHD (NB * NH)      // 64 batch*heads
#define MTOK (NB * TB)     // 8192

typedef __attribute__((ext_vector_type(8))) short short8;
typedef __attribute__((ext_vector_type(4))) float f32x4;
typedef __attribute__((ext_vector_type(16))) float f32x16;
typedef __attribute__((ext_vector_type(4))) unsigned int u32x4;

static __device__ __forceinline__ unsigned short f2bf(float f) {
  __hip_bfloat16 h = __float2bfloat16(f);
  return __builtin_bit_cast(unsigned short, h);
}

#define GLDS(g, l)                                                              \
  __builtin_amdgcn_global_load_lds((const __attribute__((address_space(1))) void*)(g), \
                                   (__attribute__((address_space(3))) void*)(l), 16, 0, 0)

// ---------------- f32 -> bf16 convert (vectorized) ----------------
__global__ __launch_bounds__(256) void cvt_kernel(const float* __restrict__ in,
                                                  unsigned short* __restrict__ out,
                                                  int n4) {
  int i = blockIdx.x * blockDim.x + threadIdx.x;
  if (i >= n4) return;
  float4 v = reinterpret_cast<const float4*>(in)[i];
  ushort4 o;
  o.x = f2bf(v.x); o.y = f2bf(v.y); o.z = f2bf(v.z); o.w = f2bf(v.w);
  reinterpret_cast<ushort4*>(out)[i] = o;
}

// ---------------- RoPE cos/sin table: tab[t*32+j] = (cos, sin)(t * 10000^(-j/32)) ----------------
__global__ __launch_bounds__(256) void rope_tab_kernel(float2* __restrict__ tab) {
  int i = blockIdx.x * 256 + threadIdx.x;  // 0..65535
  int t = i >> 5, j = i & 31;
  float ang = (float)t * __builtin_exp2f(-(float)j * 0.41524101186092029f);
  float sv, cv;
  sincosf(ang, &sv, &cv);
  tab[i] = make_float2(cv, sv);
}

// ---------------- GEMM C = A * B^T (A:[M][K] bf16, B:[N][K] bf16) ----------------
template <int EPI>  // 0: plain f32 C store; 1: QKV epilogue (RoPE + scatter)
__global__ __launch_bounds__(256) void gemm_bt(
    const unsigned short* __restrict__ Am, const unsigned short* __restrict__ Bm,
    float* __restrict__ Cout, unsigned short* __restrict__ Qo,
    unsigned short* __restrict__ Ko, unsigned short* __restrict__ Vt,
    const float2* __restrict__ Tab, int Mdim, int Ndim, int Kdim) {
  __shared__ unsigned short As[128 * 64];
  __shared__ unsigned short Bs[128 * 64];

  const int tid = threadIdx.x;
  const int lane = tid & 63;
  const int w = tid >> 6;
  const int wr = w >> 1;
  const int wc = w & 1;

  // XCD-aware bijective swizzle (grid counts are multiples of 8)
  const int nwg = gridDim.x * gridDim.y;
  int bid = blockIdx.y * gridDim.x + blockIdx.x;
  const int cpx = nwg >> 3;
  bid = (bid & 7) * cpx + (bid >> 3);
  const int m0 = (bid / gridDim.x) * 128;
  const int n0 = (bid % gridDim.x) * 128;

  const int col16 = lane & 15;
  const int seg = lane >> 4;

  f32x4 acc[4][4];
#pragma unroll
  for (int i = 0; i < 4; ++i)
#pragma unroll
    for (int j = 0; j < 4; ++j) acc[i][j] = f32x4{0.f, 0.f, 0.f, 0.f};

  const int lrow = lane >> 3;            // row within 8-row chunk
  const int jg = (lane & 7) ^ lrow;      // pre-swizzled 16B-chunk col in global

  for (int kt = 0; kt < Kdim; kt += 64) {
#pragma unroll
    for (int i = 0; i < 4; ++i) {
      const int q = w * 4 + i;           // 1KB chunk id (0..15)
      const int row = q * 8 + lrow;      // tile row 0..127  (row&7 == lrow)
      GLDS(Am + (size_t)(m0 + row) * Kdim + kt + jg * 8, As + q * 512);
      GLDS(Bm + (size_t)(n0 + row) * Kdim + kt + jg * 8, Bs + q * 512);
    }
    __syncthreads();
#pragma unroll
    for (int kk = 0; kk < 2; ++kk) {
      short8 af[4], bfr[4];
#pragma unroll
      for (int mi = 0; mi < 4; ++mi) {
        const int row = wr * 64 + mi * 16 + col16;
        const int ch = (kk * 4 + seg) ^ (row & 7);
        af[mi] = *reinterpret_cast<const short8*>(
            reinterpret_cast<const char*>(As) + row * 128 + ch * 16);
      }
#pragma unroll
      for (int ni = 0; ni < 4; ++ni) {
        const int row = wc * 64 + ni * 16 + col16;
        const int ch = (kk * 4 + seg) ^ (row & 7);
        bfr[ni] = *reinterpret_cast<const short8*>(
            reinterpret_cast<const char*>(Bs) + row * 128 + ch * 16);
      }
#pragma unroll
      for (int mi = 0; mi < 4; ++mi)
#pragma unroll
        for (int ni = 0; ni < 4; ++ni)
          acc[mi][ni] = __builtin_amdgcn_mfma_f32_16x16x32_bf16(af[mi], bfr[ni],
                                                                acc[mi][ni], 0, 0, 0);
    }
    __syncthreads();
  }

  if (EPI == 0) {
#pragma unroll
    for (int mi = 0; mi < 4; ++mi)
#pragma unroll
      for (int ni = 0; ni < 4; ++ni) {
        const int gn = n0 + wc * 64 + ni * 16 + col16;
#pragma unroll
        for (int r = 0; r < 4; ++r) {
          const int gm = m0 + wr * 64 + mi * 16 + seg * 4 + r;
          Cout[(size_t)gm * Ndim + gn] = acc[mi][ni][r];
        }
      }
  } else {
    // qkv: n in [0,1024)=Q, [1024,2048)=K, [2048,3072)=V. 128|1024 so sec uniform.
    const int sec = n0 >> 10;
    const int cbase = (n0 & 1023) + wc * 64;  // multiple of 64
    const int h = cbase >> 6;
#pragma unroll
    for (int mi = 0; mi < 4; ++mi)
#pragma unroll
      for (int ni = 0; ni < 4; ++ni) {
        const int d = ni * 16 + col16;  // 0..63 head dim
        if (sec == 2) {
          // V: store transposed [BH][D][T]; 4 consecutive t per lane -> 8B store
          const int gm0 = m0 + wr * 64 + mi * 16 + seg * 4;
          const int b = gm0 >> 11;
          const int t0 = gm0 & 2047;
          ushort4 pv;
          pv.x = f2bf(acc[mi][ni][0]);
          pv.y = f2bf(acc[mi][ni][1]);
          pv.z = f2bf(acc[mi][ni][2]);
          pv.w = f2bf(acc[mi][ni][3]);
          *reinterpret_cast<ushort4*>(
              Vt + ((size_t)((b * NH + h) * HD + d)) * TB + t0) = pv;
        } else {
          // RoPE via precomputed table: angle a_d = t * 10000^(-(d%32)/32)
          const float sgn = (d & 1) ? 1.f : -1.f;
          const int j = d & 31;
#pragma unroll
          for (int r = 0; r < 4; ++r) {
            const int gm = m0 + wr * 64 + mi * 16 + seg * 4 + r;
            const int b = gm >> 11;
            const int t = gm & 2047;
            const float v = acc[mi][ni][r];
            const float p = __shfl_xor(v, 1);  // pair partner (adjacent col)
            const float2 csv = Tab[t * 32 + j];
            float rot = v * csv.x + sgn * p * csv.y;
            // fold 1/sqrt(D) AND log2(e) into Q so attn softmax can use exp2
            if (sec == 0) rot *= 0.18033688011112042f;  // 0.125 * log2(e)
            unsigned short* dst = (sec == 0) ? Qo : Ko;
            dst[((size_t)(b * NH + h) * TB + t) * HD + d] = f2bf(rot);
          }
        }
      }
  }
}

// ---------------- causal flash attention v5: swapped 32x32 + LDS staging ----------------
// 256 blocks of 4 waves; each wave owns TWO 32-q tiles (64 q rows); block = 256 q
// rows of group G. Block processes group pair {g, 7-g} sequentially -> exactly 36
// staged 64-kv tiles per block (uniform). K [64kv][64d] and V^T [64d][64kv] staged
// to LDS via pre-swizzled global_load_lds (coalesced), double-buffered. Fragments
// read via XOR-swizzled ds_read_b128. Softmax fully in-register (swapped QK^T).
__global__ __launch_bounds__(256) void attn_kernel(
    const unsigned short* __restrict__ Q, const unsigned short* __restrict__ K,
    const unsigned short* __restrict__ Vt, unsigned short* __restrict__ Ao) {
  __shared__ unsigned short KsL[2][64 * 64];  // [buf][kv][d] swizzled, 8KB each
  __shared__ unsigned short VsL[2][64 * 64];  // [buf][d][kv] swizzled, 8KB each

  const int tid = threadIdx.x;
  const int lane = tid & 63;
  const int w = tid >> 6;
  const int bx = blockIdx.x;
  const int bh = bx & 63;       // bx == bh (mod 8): same-bh pair-blocks share an XCD
  const int pgrp = bx >> 6;     // 0..3 -> group pair {pgrp, 7-pgrp}
  const int l31 = lane & 31;
  const int hi = lane >> 5;
  const int qm = l31 - 4 * hi;  // diag mask: kill reg r if rowbase(r) > qm

  const unsigned short* Qb = Q + (size_t)bh * TB * HD;
  const unsigned short* Kb = K + (size_t)bh * TB * HD;
  const unsigned short* Vb = Vt + (size_t)bh * HD * TB;
  const int batch = bh >> 4;
  const int h = bh & 15;

#define STAGE(bufb, tt)                                                         \
  {                                                                             \
    const int kv0s = (tt) << 6;                                                 \
    _Pragma("unroll") for (int i_ = 0; i_ < 2; ++i_) {                          \
      const int slot_ = i_ * 256 + tid;                                         \
      const int row_ = slot_ >> 3;                                              \
      const int sc_ = (slot_ & 7) ^ (row_ & 7);                                 \
      GLDS(Kb + (size_t)(kv0s + row_) * HD + sc_ * 8, &KsL[bufb][slot_ * 8]);   \
      GLDS(Vb + (size_t)row_ * TB + kv0s + sc_ * 8, &VsL[bufb][slot_ * 8]);     \
    }                                                                           \
  }

#define MASKDIAG(st)                                                            \
  { _Pragma("unroll") for (int r = 0; r < 16; ++r) {                            \
      const int rowb = (r & 3) + 8 * (r >> 2);                                  \
      if (rowb > qm) st[r] = -1e30f; } }

#define PVTILE(st, V0, V1, V2, V3, O0, O1)                                      \
  {                                                                             \
    unsigned int wd[8];                                                         \
    _Pragma("unroll") for (int i = 0; i < 8; ++i) {                             \
      unsigned int t_;                                                          \
      asm("v_cvt_pk_bf16_f32 %0, %1, %2"                                        \
          : "=v"(t_) : "v"(st[2 * i]), "v"(st[2 * i + 1]));                     \
      wd[i] = t_;                                                               \
    }                                                                           \
    asm("v_permlane32_swap_b32 %0, %1" : "+v"(wd[0]), "+v"(wd[2]));             \
    asm("v_permlane32_swap_b32 %0, %1" : "+v"(wd[1]), "+v"(wd[3]));             \
    asm("v_permlane32_swap_b32 %0, %1" : "+v"(wd[4]), "+v"(wd[6]));             \
    asm("v_permlane32_swap_b32 %0, %1" : "+v"(wd[5]), "+v"(wd[7]));             \
    u32x4 f0 = {wd[0], wd[1], wd[2], wd[3]};                                    \
    u32x4 f1 = {wd[4], wd[5], wd[6], wd[7]};                                    \
    short8 p0 = __builtin_bit_cast(short8, f0);                                 \
    short8 p1 = __builtin_bit_cast(short8, f1);                                 \
    __builtin_amdgcn_s_setprio(1);                                              \
    O0 = __builtin_amdgcn_mfma_f32_32x32x16_bf16(V0, p0, O0, 0, 0, 0);          \
    O1 = __builtin_amdgcn_mfma_f32_32x32x16_bf16(V1, p0, O1, 0, 0, 0);          \
    O0 = __builtin_amdgcn_mfma_f32_32x32x16_bf16(V2, p1, O0, 0, 0, 0);          \
    O1 = __builtin_amdgcn_mfma_f32_32x32x16_bf16(V3, p1, O1, 0, 0, 0);          \
    __builtin_amdgcn_s_setprio(0);                                              \
  }

// Process one 32-q tile against the staged 64-kv tile.
#define PROC_QT(QF, O0, O1, MROW, LSUM, Q0X)                                    \
  if (kv0 <= (Q0X)) {                                                           \
    const bool a1_ = (kv0 + 32 <= (Q0X));                                       \
    f32x16 s0_, s1_;                                                            \
    _Pragma("unroll") for (int r = 0; r < 16; ++r) { s0_[r] = 0.f; s1_[r] = 0.f; } \
    __builtin_amdgcn_s_setprio(1);                                              \
    _Pragma("unroll") for (int s = 0; s < 4; ++s)                               \
      s0_ = __builtin_amdgcn_mfma_f32_32x32x16_bf16(kf0[s], QF[s], s0_, 0, 0, 0); \
    if (a1_)                                                                    \
      _Pragma("unroll") for (int s = 0; s < 4; ++s)                             \
        s1_ = __builtin_amdgcn_mfma_f32_32x32x16_bf16(kf1[s], QF[s], s1_, 0, 0, 0); \
    __builtin_amdgcn_s_setprio(0);                                              \
    if (kv0 == (Q0X)) MASKDIAG(s0_);                                            \
    if (a1_ && kv0 + 32 == (Q0X)) MASKDIAG(s1_);                                \
    float mx[8];                                                                \
    _Pragma("unroll") for (int i = 0; i < 8; ++i)                               \
      mx[i] = fmaxf(s0_[2 * i], s0_[2 * i + 1]);                                \
    if (a1_)                                                                    \
      _Pragma("unroll") for (int i = 0; i < 8; ++i)                             \
        mx[i] = fmaxf(mx[i], fmaxf(s1_[2 * i], s1_[2 * i + 1]));                \
    _Pragma("unroll") for (int i = 0; i < 4; ++i) mx[i] = fmaxf(mx[i], mx[i + 4]); \
    float pm = fmaxf(fmaxf(mx[0], mx[1]), fmaxf(mx[2], mx[3]));                 \
    pm = fmaxf(pm, __shfl_xor(pm, 32));                                         \
    if (!__all(pm - MROW <= 8.f)) {                                             \
      const float mn = fmaxf(MROW, pm);                                         \
      const float fs = __builtin_exp2f(MROW - mn);                              \
      MROW = mn;                                                                \
      LSUM *= fs;                                                               \
      _Pragma("unroll") for (int r = 0; r < 16; ++r) { O0[r] *= fs; O1[r] *= fs; } \
    }                                                                           \
    float sm[8];                                                                \
    _Pragma("unroll") for (int i = 0; i < 8; ++i) {                             \
      s0_[2 * i] = __builtin_exp2f(s0_[2 * i] - MROW);                          \
      s0_[2 * i + 1] = __builtin_exp2f(s0_[2 * i + 1] - MROW);                  \
      sm[i] = s0_[2 * i] + s0_[2 * i + 1];                                      \
    }                                                                           \
    if (a1_)                                                                    \
      _Pragma("unroll") for (int i = 0; i < 8; ++i) {                           \
        s1_[2 * i] = __builtin_exp2f(s1_[2 * i] - MROW);                        \
        s1_[2 * i + 1] = __builtin_exp2f(s1_[2 * i + 1] - MROW);                \
        sm[i] += s1_[2 * i] + s1_[2 * i + 1];                                   \
      }                                                                         \
    _Pragma("unroll") for (int i = 0; i < 4; ++i) sm[i] += sm[i + 4];           \
    float rs = (sm[0] + sm[1]) + (sm[2] + sm[3]);                               \
    rs += __shfl_xor(rs, 32);                                                   \
    LSUM += rs;                                                                 \
    PVTILE(s0_, vf[0][0][0], vf[0][1][0], vf[0][0][1], vf[0][1][1], O0, O1);    \
    if (a1_) PVTILE(s1_, vf[1][0][0], vf[1][1][0], vf[1][0][1], vf[1][1][1], O0, O1); \
  }

#pragma unroll 1
  for (int ph = 0; ph < 2; ++ph) {
    const int G = ph ? (7 - pgrp) : pgrp;
    const int qbase = (G << 8) + (w << 6);
    const int q0a = qbase;
    const int q0b = qbase + 32;

    short8 qfa[4], qfb[4];
#pragma unroll
    for (int s = 0; s < 4; ++s) {
      qfa[s] = *reinterpret_cast<const short8*>(
          Qb + (size_t)(q0a + l31) * HD + hi * 8 + s * 16);
      qfb[s] = *reinterpret_cast<const short8*>(
          Qb + (size_t)(q0b + l31) * HD + hi * 8 + s * 16);
    }

    f32x16 oa0, oa1, ob0, ob1;
#pragma unroll
    for (int r = 0; r < 16; ++r) { oa0[r] = 0.f; oa1[r] = 0.f; ob0[r] = 0.f; ob1[r] = 0.f; }
    float mra = -1e30f, la = 0.f, mrb = -1e30f, lb = 0.f;

    const int ntile = 4 * G + 4;
    STAGE(0, 0);
    __syncthreads();

    int cur = 0;
    for (int kt = 0; kt < ntile; ++kt) {
      if (kt + 1 < ntile) STAGE(cur ^ 1, kt + 1);
      const int kv0 = kt << 6;

      if (kv0 <= q0b) {
        const char* kb = reinterpret_cast<const char*>(&KsL[cur][0]);
        const char* vb = reinterpret_cast<const char*>(&VsL[cur][0]);
        short8 kf0[4], kf1[4];
#pragma unroll
        for (int s = 0; s < 4; ++s) {
          const int r0 = l31;
          const int r1 = 32 + l31;
          kf0[s] = *reinterpret_cast<const short8*>(
              kb + r0 * 128 + (((2 * s + hi) ^ (r0 & 7)) << 4));
          kf1[s] = *reinterpret_cast<const short8*>(
              kb + r1 * 128 + (((2 * s + hi) ^ (r1 & 7)) << 4));
        }
        short8 vf[2][2][2];  // [sub][dh][kk]
#pragma unroll
        for (int sub = 0; sub < 2; ++sub)
#pragma unroll
          for (int dh = 0; dh < 2; ++dh)
#pragma unroll
            for (int kk = 0; kk < 2; ++kk) {
              const int row = dh * 32 + l31;
              const int ch = (sub * 4 + 2 * kk + hi) ^ (row & 7);
              vf[sub][dh][kk] = *reinterpret_cast<const short8*>(
                  vb + row * 128 + (ch << 4));
            }

        PROC_QT(qfa, oa0, oa1, mra, la, q0a);
        PROC_QT(qfb, ob0, ob1, mrb, lb, q0b);
      }

      __syncthreads();
      cur ^= 1;
    }

    // epilogue: normalize and store both q-tiles
    {
      const float inva = 1.f / la;
      unsigned short* Aor = Ao + ((size_t)(batch * TB + q0a + l31)) * NE + (h << 6);
#pragma unroll
      for (int dt = 0; dt < 2; ++dt)
#pragma unroll
        for (int qd = 0; qd < 4; ++qd) {
          ushort4 pk;
          pk.x = f2bf((dt ? oa1[4 * qd + 0] : oa0[4 * qd + 0]) * inva);
          pk.y = f2bf((dt ? oa1[4 * qd + 1] : oa0[4 * qd + 1]) * inva);
          pk.z = f2bf((dt ? oa1[4 * qd + 2] : oa0[4 * qd + 2]) * inva);
          pk.w = f2bf((dt ? oa1[4 * qd + 3] : oa0[4 * qd + 3]) * inva);
          *reinterpret_cast<ushort4*>(Aor + dt * 32 + 8 * qd + 4 * hi) = pk;
        }
      const float invb = 1.f / lb;
      unsigned short* Aor2 = Ao + ((size_t)(batch * TB + q0b + l31)) * NE + (h << 6);
#pragma unroll
      for (int dt = 0; dt < 2; ++dt)
#pragma unroll
        for (int qd = 0; qd < 4; ++qd) {
          ushort4 pk;
          pk.x = f2bf((dt ? ob1[4 * qd + 0] : ob0[4 * qd + 0]) * invb);
          pk.y = f2bf((dt ? ob1[4 * qd + 1] : ob0[4 * qd + 1]) * invb);
          pk.z = f2bf((dt ? ob1[4 * qd + 2] : ob0[4 * qd + 2]) * invb);
          pk.w = f2bf((dt ? ob1[4 * qd + 3] : ob0[4 * qd + 3]) * invb);
          *reinterpret_cast<ushort4*>(Aor2 + dt * 32 + 8 * qd + 4 * hi) = pk;
        }
    }
  }
#undef STAGE
#undef MASKDIAG
#undef PVTILE
#undef PROC_QT
}

// ---------------- launch ----------------
extern "C" void kernel_launch(void* const* d_in, const int* in_sizes, int n_in,
                              void* d_out, int out_size, void* d_ws, size_t ws_size,
                              hipStream_t stream) {
  const float* x = (const float*)d_in[0];
  const float* w_attn = (const float*)d_in[1];
  const float* w_proj = (const float*)d_in[2];
  float* out = (float*)d_out;
  char* ws = (char*)d_ws;

  const size_t SZ_XB = (size_t)MTOK * NE * 2;        // 16 MiB
  const size_t SZ_WA = (size_t)3 * NE * NE * 2;      // 6 MiB
  const size_t SZ_WP = (size_t)NE * NE * 2;          // 2 MiB
  const size_t SZ_T = (size_t)BHD * TB * HD * 2;     // 16 MiB

  unsigned short* xb = (unsigned short*)(ws);
  unsigned short* wab = (unsigned short*)(ws + SZ_XB);
  unsigned short* wpb = (unsigned short*)(ws + SZ_XB + SZ_WA);
  unsigned short* Qs = (unsigned short*)(ws + SZ_XB + SZ_WA + SZ_WP);
  unsigned short* Ks = (unsigned short*)(ws + SZ_XB + SZ_WA + SZ_WP + SZ_T);
  unsigned short* Vt = (unsigned short*)(ws + SZ_XB + SZ_WA + SZ_WP + 2 * SZ_T);
  unsigned short* Ao = (unsigned short*)(ws + SZ_XB + SZ_WA + SZ_WP + 3 * SZ_T);
  // RoPE table lives in Ao's space: needed only by gemm<1>, dead before attn writes Ao
  float2* tab = (float2*)Ao;

  hipLaunchKernelGGL(cvt_kernel, dim3(MTOK * NE / 4 / 256), dim3(256), 0, stream,
                     x, xb, MTOK * NE / 4);
  hipLaunchKernelGGL(cvt_kernel, dim3(3 * NE * NE / 4 / 256), dim3(256), 0, stream,
                     w_attn, wab, 3 * NE * NE / 4);
  hipLaunchKernelGGL(cvt_kernel, dim3(NE * NE / 4 / 256), dim3(256), 0, stream,
                     w_proj, wpb, NE * NE / 4);
  hipLaunchKernelGGL(rope_tab_kernel, dim3(TB * 32 / 256), dim3(256), 0, stream, tab);

  hipLaunchKernelGGL((gemm_bt<1>), dim3(3 * NE / 128, MTOK / 128), dim3(256), 0,
                     stream, xb, wab, nullptr, Qs, Ks, Vt, tab, MTOK, 3 * NE, NE);

  // 256 blocks: bh = bx&63, pair-group = bx>>6; each block = 256 q rows x 2 phases
  hipLaunchKernelGGL(attn_kernel, dim3(256), dim3(256), 0, stream,
                     Qs, Ks, Vt, Ao);

  hipLaunchKernelGGL((gemm_bt<0>), dim3(NE / 128, MTOK / 128), dim3(256), 0,
                     stream, Ao, wpb, out, nullptr, nullptr, nullptr,
                     (const float2*)nullptr, MTOK, NE, NE);
}

// Round 8
// 223.362 us; speedup vs baseline: 1.1251x; 1.0700x over previous
//
#include <hip/hip_runtime.h>
#include <hip/hip_bf16.h>

#define TB 2048
#define NH 16
#define HD 64
#define NE 1024
#define NB 4
#define BHD (NB * NH)      // 64 batch*heads
#define MTOK (NB * TB)     // 8192

typedef __attribute__((ext_vector_type(8))) short short8;
typedef __attribute__((ext_vector_type(4))) float f32x4;
typedef __attribute__((ext_vector_type(16))) float f32x16;
typedef __attribute__((ext_vector_type(4))) unsigned int u32x4;

static __device__ __forceinline__ unsigned short f2bf(float f) {
  __hip_bfloat16 h = __float2bfloat16(f);
  return __builtin_bit_cast(unsigned short, h);
}

#define GLDS(g, l)                                                              \
  __builtin_amdgcn_global_load_lds((const __attribute__((address_space(1))) void*)(g), \
                                   (__attribute__((address_space(3))) void*)(l), 16, 0, 0)

// ---------------- f32 -> bf16 convert (vectorized) ----------------
__global__ __launch_bounds__(256) void cvt_kernel(const float* __restrict__ in,
                                                  unsigned short* __restrict__ out,
                                                  int n4) {
  int i = blockIdx.x * blockDim.x + threadIdx.x;
  if (i >= n4) return;
  float4 v = reinterpret_cast<const float4*>(in)[i];
  ushort4 o;
  o.x = f2bf(v.x); o.y = f2bf(v.y); o.z = f2bf(v.z); o.w = f2bf(v.w);
  reinterpret_cast<ushort4*>(out)[i] = o;
}

// ---------------- RoPE cos/sin table: tab[t*32+j] = (cos, sin)(t * 10000^(-j/32)) ----------------
__global__ __launch_bounds__(256) void rope_tab_kernel(float2* __restrict__ tab) {
  int i = blockIdx.x * 256 + threadIdx.x;  // 0..65535
  int t = i >> 5, j = i & 31;
  float ang = (float)t * __builtin_exp2f(-(float)j * 0.41524101186092029f);
  float sv, cv;
  sincosf(ang, &sv, &cv);
  tab[i] = make_float2(cv, sv);
}

// ---------------- GEMM C = A * B^T (A:[M][K] bf16, B:[N][K] bf16) ----------------
// EPI==1 epilogue writes K and V in FRAGMENT-MAJOR layout (4KB per 32-kv block)
// so attention's MFMA operand loads are fully coalesced (lane-contiguous 16B):
//   K2 block idx = (d>>4)*512 + ((d>>3)&1)*256 + (t&31)*8 + (d&7)
//   V2 block idx = ((d>>5)*2 + ((t&31)>>4))*512 + ((t>>3)&1)*256 + (d&31)*8 + (t&7)
template <int EPI>  // 0: plain f32 C store; 1: QKV epilogue (RoPE + scatter)
__global__ __launch_bounds__(256) void gemm_bt(
    const unsigned short* __restrict__ Am, const unsigned short* __restrict__ Bm,
    float* __restrict__ Cout, unsigned short* __restrict__ Qo,
    unsigned short* __restrict__ Ko, unsigned short* __restrict__ Vt,
    const float2* __restrict__ Tab, int Mdim, int Ndim, int Kdim) {
  __shared__ unsigned short As[128 * 64];
  __shared__ unsigned short Bs[128 * 64];

  const int tid = threadIdx.x;
  const int lane = tid & 63;
  const int w = tid >> 6;
  const int wr = w >> 1;
  const int wc = w & 1;

  // XCD-aware bijective swizzle (grid counts are multiples of 8)
  const int nwg = gridDim.x * gridDim.y;
  int bid = blockIdx.y * gridDim.x + blockIdx.x;
  const int cpx = nwg >> 3;
  bid = (bid & 7) * cpx + (bid >> 3);
  const int m0 = (bid / gridDim.x) * 128;
  const int n0 = (bid % gridDim.x) * 128;

  const int col16 = lane & 15;
  const int seg = lane >> 4;

  f32x4 acc[4][4];
#pragma unroll
  for (int i = 0; i < 4; ++i)
#pragma unroll
    for (int j = 0; j < 4; ++j) acc[i][j] = f32x4{0.f, 0.f, 0.f, 0.f};

  const int lrow = lane >> 3;            // row within 8-row chunk
  const int jg = (lane & 7) ^ lrow;      // pre-swizzled 16B-chunk col in global

  for (int kt = 0; kt < Kdim; kt += 64) {
#pragma unroll
    for (int i = 0; i < 4; ++i) {
      const int q = w * 4 + i;           // 1KB chunk id (0..15)
      const int row = q * 8 + lrow;      // tile row 0..127  (row&7 == lrow)
      GLDS(Am + (size_t)(m0 + row) * Kdim + kt + jg * 8, As + q * 512);
      GLDS(Bm + (size_t)(n0 + row) * Kdim + kt + jg * 8, Bs + q * 512);
    }
    __syncthreads();
#pragma unroll
    for (int kk = 0; kk < 2; ++kk) {
      short8 af[4], bfr[4];
#pragma unroll
      for (int mi = 0; mi < 4; ++mi) {
        const int row = wr * 64 + mi * 16 + col16;
        const int ch = (kk * 4 + seg) ^ (row & 7);
        af[mi] = *reinterpret_cast<const short8*>(
            reinterpret_cast<const char*>(As) + row * 128 + ch * 16);
      }
#pragma unroll
      for (int ni = 0; ni < 4; ++ni) {
        const int row = wc * 64 + ni * 16 + col16;
        const int ch = (kk * 4 + seg) ^ (row & 7);
        bfr[ni] = *reinterpret_cast<const short8*>(
            reinterpret_cast<const char*>(Bs) + row * 128 + ch * 16);
      }
#pragma unroll
      for (int mi = 0; mi < 4; ++mi)
#pragma unroll
        for (int ni = 0; ni < 4; ++ni)
          acc[mi][ni] = __builtin_amdgcn_mfma_f32_16x16x32_bf16(af[mi], bfr[ni],
                                                                acc[mi][ni], 0, 0, 0);
    }
    __syncthreads();
  }

  if (EPI == 0) {
#pragma unroll
    for (int mi = 0; mi < 4; ++mi)
#pragma unroll
      for (int ni = 0; ni < 4; ++ni) {
        const int gn = n0 + wc * 64 + ni * 16 + col16;
#pragma unroll
        for (int r = 0; r < 4; ++r) {
          const int gm = m0 + wr * 64 + mi * 16 + seg * 4 + r;
          Cout[(size_t)gm * Ndim + gn] = acc[mi][ni][r];
        }
      }
  } else {
    // qkv: n in [0,1024)=Q, [1024,2048)=K, [2048,3072)=V. 128|1024 so sec uniform.
    const int sec = n0 >> 10;
    const int cbase = (n0 & 1023) + wc * 64;  // multiple of 64
    const int h = cbase >> 6;
#pragma unroll
    for (int mi = 0; mi < 4; ++mi)
#pragma unroll
      for (int ni = 0; ni < 4; ++ni) {
        const int d = ni * 16 + col16;  // 0..63 head dim
        if (sec == 2) {
          // V2 fragment-major: 4 consecutive t (same d) stay contiguous (8B store)
          const int gm0 = m0 + wr * 64 + mi * 16 + seg * 4;
          const int b = gm0 >> 11;
          const int t0 = gm0 & 2047;
          ushort4 pv;
          pv.x = f2bf(acc[mi][ni][0]);
          pv.y = f2bf(acc[mi][ni][1]);
          pv.z = f2bf(acc[mi][ni][2]);
          pv.w = f2bf(acc[mi][ni][3]);
          const size_t vaddr = (size_t)(b * NH + h) * TB * HD + (size_t)(t0 >> 5) * 2048 +
                               ((d >> 5) * 2 + ((t0 & 31) >> 4)) * 512 +
                               ((t0 >> 3) & 1) * 256 + (d & 31) * 8 + (t0 & 7);
          *reinterpret_cast<ushort4*>(Vt + vaddr) = pv;
        } else {
          // RoPE via precomputed table: angle a_d = t * 10000^(-(d%32)/32)
          const float sgn = (d & 1) ? 1.f : -1.f;
          const int j = d & 31;
#pragma unroll
          for (int r = 0; r < 4; ++r) {
            const int gm = m0 + wr * 64 + mi * 16 + seg * 4 + r;
            const int b = gm >> 11;
            const int t = gm & 2047;
            const float v = acc[mi][ni][r];
            const float p = __shfl_xor(v, 1);  // pair partner (adjacent col)
            const float2 csv = Tab[t * 32 + j];
            float rot = v * csv.x + sgn * p * csv.y;
            if (sec == 0) {
              // fold 1/sqrt(D) AND log2(e) into Q so attn softmax can use exp2
              rot *= 0.18033688011112042f;  // 0.125 * log2(e)
              Qo[((size_t)(b * NH + h) * TB + t) * HD + d] = f2bf(rot);
            } else {
              // K2 fragment-major
              const size_t kaddr = (size_t)(b * NH + h) * TB * HD +
                                   (size_t)(t >> 5) * 2048 + (d >> 4) * 512 +
                                   ((d >> 3) & 1) * 256 + (t & 31) * 8 + (d & 7);
              Ko[kaddr] = f2bf(rot);
            }
          }
        }
      }
  }
}

// ---------------- causal flash attention v6: swapped 32x32, fragment-major K/V ----------------
// r6 structure (balanced wave pairs {pr, 63-pr}, 2048 waves, no LDS, no barriers)
// with K2/V2 fragment-major layouts: every MFMA operand load is lane-contiguous
// 16B x 64 lanes = 1024B (8 cache lines vs 64 for the old strided gather).
__global__ __launch_bounds__(256) void attn_kernel(
    const unsigned short* __restrict__ Q, const unsigned short* __restrict__ K2,
    const unsigned short* __restrict__ V2, unsigned short* __restrict__ Ao) {
  const int tid = threadIdx.x;
  const int lane = tid & 63;
  const int w = tid >> 6;
  // XCD remap: 8 consecutive bh per XCD (K2/V2 512KB x 8 bh = 4MB = one L2)
  const int L = ((int)blockIdx.x & 7) * 64 + ((int)blockIdx.x >> 3);
  const int wid = L * 4 + w;            // 0..2047
  const int bh = wid >> 5;              // 0..63
  const int pr = wid & 31;              // 0..31
  const int l31 = lane & 31;
  const int hi = lane >> 5;
  const int qm = l31 - 4 * hi;          // diag mask: kill reg r if rowbase(r) > qm

  const unsigned short* Qb = Q + (size_t)bh * TB * HD;
  const unsigned short* K2b = K2 + (size_t)bh * TB * HD;
  const unsigned short* V2b = V2 + (size_t)bh * TB * HD;
  const int fo = hi * 256 + l31 * 8;    // per-lane offset within a fragment group

  const int batch = bh >> 4;
  const int h = bh & 15;

#define MASKDIAG(st)                                                            \
  { _Pragma("unroll") for (int r = 0; r < 16; ++r) {                            \
      const int rowb = (r & 3) + 8 * (r >> 2);                                  \
      if (rowb > qm) st[r] = -1e30f; } }

#define PVTILE(st, V0, V1, V2x, V3)                                             \
  {                                                                             \
    unsigned int wd[8];                                                         \
    _Pragma("unroll") for (int i = 0; i < 8; ++i) {                             \
      unsigned int t_;                                                          \
      asm("v_cvt_pk_bf16_f32 %0, %1, %2"                                        \
          : "=v"(t_) : "v"(st[2 * i]), "v"(st[2 * i + 1]));                     \
      wd[i] = t_;                                                               \
    }                                                                           \
    asm("v_permlane32_swap_b32 %0, %1" : "+v"(wd[0]), "+v"(wd[2]));             \
    asm("v_permlane32_swap_b32 %0, %1" : "+v"(wd[1]), "+v"(wd[3]));             \
    asm("v_permlane32_swap_b32 %0, %1" : "+v"(wd[4]), "+v"(wd[6]));             \
    asm("v_permlane32_swap_b32 %0, %1" : "+v"(wd[5]), "+v"(wd[7]));             \
    u32x4 f0 = {wd[0], wd[1], wd[2], wd[3]};                                    \
    u32x4 f1 = {wd[4], wd[5], wd[6], wd[7]};                                    \
    short8 p0 = __builtin_bit_cast(short8, f0);                                 \
    short8 p1 = __builtin_bit_cast(short8, f1);                                 \
    __builtin_amdgcn_s_setprio(1);                                              \
    o0 = __builtin_amdgcn_mfma_f32_32x32x16_bf16(V0, p0, o0, 0, 0, 0);          \
    o1 = __builtin_amdgcn_mfma_f32_32x32x16_bf16(V1, p0, o1, 0, 0, 0);          \
    o0 = __builtin_amdgcn_mfma_f32_32x32x16_bf16(V2x, p1, o0, 0, 0, 0);         \
    o1 = __builtin_amdgcn_mfma_f32_32x32x16_bf16(V3, p1, o1, 0, 0, 0);          \
    __builtin_amdgcn_s_setprio(0);                                              \
  }

#pragma unroll 1
  for (int ph = 0; ph < 2; ++ph) {
    const int qt = ph ? (63 - pr) : pr;
    const int q0 = qt << 5;

    short8 qf[4];
#pragma unroll
    for (int s = 0; s < 4; ++s)
      qf[s] = *reinterpret_cast<const short8*>(
          Qb + (size_t)(q0 + l31) * HD + hi * 8 + s * 16);

    f32x16 o0, o1;
#pragma unroll
    for (int r = 0; r < 16; ++r) { o0[r] = 0.f; o1[r] = 0.f; }
    float mrow = -1e30f, lsum = 0.f;

    // preload K fragments for iter 0 (kv blocks 0 and 1) — coalesced
    short8 kf0[4], kf1[4];
#pragma unroll
    for (int s = 0; s < 4; ++s)
      kf0[s] = *reinterpret_cast<const short8*>(K2b + s * 512 + fo);
    if (q0 >= 32)
#pragma unroll
      for (int s = 0; s < 4; ++s)
        kf1[s] = *reinterpret_cast<const short8*>(K2b + 2048 + s * 512 + fo);

    const int LI = qt >> 1;
    for (int kt = 0; kt <= LI; ++kt) {
      const int kv0 = kt << 6;
      const bool two = (kv0 + 32 <= q0);

      // QK^T (S^T accumulate) with preloaded K frags
      f32x16 s0, s1;
#pragma unroll
      for (int r = 0; r < 16; ++r) { s0[r] = 0.f; s1[r] = 0.f; }
      __builtin_amdgcn_s_setprio(1);
#pragma unroll
      for (int s = 0; s < 4; ++s)
        s0 = __builtin_amdgcn_mfma_f32_32x32x16_bf16(kf0[s], qf[s], s0, 0, 0, 0);
      if (two)
#pragma unroll
        for (int s = 0; s < 4; ++s)
          s1 = __builtin_amdgcn_mfma_f32_32x32x16_bf16(kf1[s], qf[s], s1, 0, 0, 0);
      __builtin_amdgcn_s_setprio(0);

      // V frags for THIS iter (fragment-major, coalesced; consumed after softmax)
      const unsigned short* Va = V2b + (size_t)(2 * kt) * 2048 + fo;
      short8 va0 = *reinterpret_cast<const short8*>(Va);
      short8 va1 = *reinterpret_cast<const short8*>(Va + 1024);
      short8 va2 = *reinterpret_cast<const short8*>(Va + 512);
      short8 va3 = *reinterpret_cast<const short8*>(Va + 1536);
      short8 vb0, vb1, vb2, vb3;
      if (two) {
        const unsigned short* Vbp = Va + 2048;
        vb0 = *reinterpret_cast<const short8*>(Vbp);
        vb1 = *reinterpret_cast<const short8*>(Vbp + 1024);
        vb2 = *reinterpret_cast<const short8*>(Vbp + 512);
        vb3 = *reinterpret_cast<const short8*>(Vbp + 1536);
      }

      // K frags for NEXT iter (coalesced prefetch)
      if (kt < LI) {
        const unsigned short* Kn = K2b + (size_t)(2 * kt + 2) * 2048;
#pragma unroll
        for (int s = 0; s < 4; ++s)
          kf0[s] = *reinterpret_cast<const short8*>(Kn + s * 512 + fo);
        if (kv0 + 96 <= q0)
#pragma unroll
          for (int s = 0; s < 4; ++s)
            kf1[s] = *reinterpret_cast<const short8*>(Kn + 2048 + s * 512 + fo);
      }

      // causal mask on the diagonal 32x32 tile
      if (kv0 == q0) MASKDIAG(s0);
      if (two && (kv0 + 32 == q0)) MASKDIAG(s1);

      // online softmax (exp2 domain; Q pre-scaled by 0.125*log2e), defer-max,
      // tree-shaped reductions.
      float mx[8];
#pragma unroll
      for (int i = 0; i < 8; ++i) mx[i] = fmaxf(s0[2 * i], s0[2 * i + 1]);
      if (two)
#pragma unroll
        for (int i = 0; i < 8; ++i)
          mx[i] = fmaxf(mx[i], fmaxf(s1[2 * i], s1[2 * i + 1]));
#pragma unroll
      for (int i = 0; i < 4; ++i) mx[i] = fmaxf(mx[i], mx[i + 4]);
      float pm = fmaxf(fmaxf(mx[0], mx[1]), fmaxf(mx[2], mx[3]));
      pm = fmaxf(pm, __shfl_xor(pm, 32));
      if (!__all(pm - mrow <= 8.f)) {
        const float mn = fmaxf(mrow, pm);
        const float fs = __builtin_exp2f(mrow - mn);
        mrow = mn;
        lsum *= fs;
#pragma unroll
        for (int r = 0; r < 16; ++r) { o0[r] *= fs; o1[r] *= fs; }
      }
      float sm[8];
#pragma unroll
      for (int i = 0; i < 8; ++i) {
        s0[2 * i] = __builtin_exp2f(s0[2 * i] - mrow);
        s0[2 * i + 1] = __builtin_exp2f(s0[2 * i + 1] - mrow);
        sm[i] = s0[2 * i] + s0[2 * i + 1];
      }
      if (two)
#pragma unroll
        for (int i = 0; i < 8; ++i) {
          s1[2 * i] = __builtin_exp2f(s1[2 * i] - mrow);
          s1[2 * i + 1] = __builtin_exp2f(s1[2 * i + 1] - mrow);
          sm[i] += s1[2 * i] + s1[2 * i + 1];
        }
#pragma unroll
      for (int i = 0; i < 4; ++i) sm[i] += sm[i + 4];
      float rs = (sm[0] + sm[1]) + (sm[2] + sm[3]);
      rs += __shfl_xor(rs, 32);
      lsum += rs;

      PVTILE(s0, va0, va1, va2, va3);
      if (two) PVTILE(s1, vb0, vb1, vb2, vb3);
    }

    // epilogue: normalize (lsum lane-uniform per q) and store bf16 to Ao[B][T][E]
    const float inv = 1.f / lsum;
    unsigned short* Aor = Ao + ((size_t)(batch * TB + q0 + l31)) * NE + (h << 6);
#pragma unroll
    for (int dt = 0; dt < 2; ++dt) {
#pragma unroll
      for (int qd = 0; qd < 4; ++qd) {
        ushort4 pk;
        pk.x = f2bf((dt ? o1[4 * qd + 0] : o0[4 * qd + 0]) * inv);
        pk.y = f2bf((dt ? o1[4 * qd + 1] : o0[4 * qd + 1]) * inv);
        pk.z = f2bf((dt ? o1[4 * qd + 2] : o0[4 * qd + 2]) * inv);
        pk.w = f2bf((dt ? o1[4 * qd + 3] : o0[4 * qd + 3]) * inv);
        *reinterpret_cast<ushort4*>(Aor + dt * 32 + 8 * qd + 4 * hi) = pk;
      }
    }
  }
#undef MASKDIAG
#undef PVTILE
}

// ---------------- launch ----------------
extern "C" void kernel_launch(void* const* d_in, const int* in_sizes, int n_in,
                              void* d_out, int out_size, void* d_ws, size_t ws_size,
                              hipStream_t stream) {
  const float* x = (const float*)d_in[0];
  const float* w_attn = (const float*)d_in[1];
  const float* w_proj = (const float*)d_in[2];
  float* out = (float*)d_out;
  char* ws = (char*)d_ws;

  const size_t SZ_XB = (size_t)MTOK * NE * 2;        // 16 MiB
  const size_t SZ_WA = (size_t)3 * NE * NE * 2;      // 6 MiB
  const size_t SZ_WP = (size_t)NE * NE * 2;          // 2 MiB
  const size_t SZ_T = (size_t)BHD * TB * HD * 2;     // 16 MiB

  unsigned short* xb = (unsigned short*)(ws);
  unsigned short* wab = (unsigned short*)(ws + SZ_XB);
  unsigned short* wpb = (unsigned short*)(ws + SZ_XB + SZ_WA);
  unsigned short* Qs = (unsigned short*)(ws + SZ_XB + SZ_WA + SZ_WP);
  unsigned short* K2 = (unsigned short*)(ws + SZ_XB + SZ_WA + SZ_WP + SZ_T);
  unsigned short* V2 = (unsigned short*)(ws + SZ_XB + SZ_WA + SZ_WP + 2 * SZ_T);
  unsigned short* Ao = (unsigned short*)(ws + SZ_XB + SZ_WA + SZ_WP + 3 * SZ_T);
  // RoPE table lives in Ao's space: needed only by gemm<1>, dead before attn writes Ao
  float2* tab = (float2*)Ao;

  hipLaunchKernelGGL(cvt_kernel, dim3(MTOK * NE / 4 / 256), dim3(256), 0, stream,
                     x, xb, MTOK * NE / 4);
  hipLaunchKernelGGL(cvt_kernel, dim3(3 * NE * NE / 4 / 256), dim3(256), 0, stream,
                     w_attn, wab, 3 * NE * NE / 4);
  hipLaunchKernelGGL(cvt_kernel, dim3(NE * NE / 4 / 256), dim3(256), 0, stream,
                     w_proj, wpb, NE * NE / 4);
  hipLaunchKernelGGL(rope_tab_kernel, dim3(TB * 32 / 256), dim3(256), 0, stream, tab);

  hipLaunchKernelGGL((gemm_bt<1>), dim3(3 * NE / 128, MTOK / 128), dim3(256), 0,
                     stream, xb, wab, nullptr, Qs, K2, V2, tab, MTOK, 3 * NE, NE);

  // 512 blocks x 4 waves; each wave does q-tile pair {pr, 63-pr} for one bh
  hipLaunchKernelGGL(attn_kernel, dim3(512), dim3(256), 0, stream,
                     Qs, K2, V2, Ao);

  hipLaunchKernelGGL((gemm_bt<0>), dim3(NE / 128, MTOK / 128), dim3(256), 0,
                     stream, Ao, wpb, out, nullptr, nullptr, nullptr,
                     (const float2*)nullptr, MTOK, NE, NE);
}